// Round 1
// baseline (70234.906 us; speedup 1.0000x reference)
//
#include <hip/hip_runtime.h>
#include <math.h>

// ---------------- config ----------------
#define TF_PARTITIONABLE 1   // jax threefry_partitionable (default True since jax 0.4.36)

static constexpr int Bn=64, Ln=512, En=512, Tn=512, Sn=512, Pn=256, An=1024, Dn=1024, Gn=128, Vn=148;
static constexpr int G4A = 4096;            // 4*A == 4*D
static constexpr int KPROJ = Dn + En;       // 1536
static constexpr int ACH = 8,  ACK = 224;   // att gates K=1792 = 8*224
static constexpr int DCH = 16, DCK = 160;   // dec gates K=2560 = 16*160
static constexpr long LOGITS_OFF = 0;
static constexpr long ALIGNS_OFF = (long)Bn*Tn*Vn;               // 4,849,664
static constexpr long PARAMS_OFF = ALIGNS_OFF + (long)Bn*Tn*Ln;  // 21,626,880

// ---------------- threefry2x32 (jax-exact) ----------------
struct TFo { unsigned a, b; };
static constexpr TFo htf(unsigned k1, unsigned k2, unsigned x0, unsigned x1) {
  unsigned ks2 = k1 ^ k2 ^ 0x1BD11BDAu;
  unsigned ks[3] = {k1, k2, ks2};
  const unsigned ra[4] = {13u,15u,26u,6u}, rb[4] = {17u,29u,16u,24u};
  x0 += k1; x1 += k2;
  for (int g = 0; g < 5; ++g) {
    const unsigned* r = (g % 2 == 0) ? ra : rb;
    for (int i = 0; i < 4; ++i) { x0 += x1; x1 = (x1 << r[i]) | (x1 >> (32u - r[i])); x1 ^= x0; }
    x0 += ks[(g+1)%3]; x1 += ks[(g+2)%3] + (unsigned)(g+1);
  }
  return TFo{x0, x1};
}
#if TF_PARTITIONABLE
static constexpr TFo DK1 = htf(0u,42u,0u,0u);   // split(key(42))[0]
static constexpr TFo DK2 = htf(0u,42u,0u,1u);   // split(key(42))[1]
#else
static constexpr TFo S02 = htf(0u,42u,0u,2u);
static constexpr TFo S13 = htf(0u,42u,1u,3u);
static constexpr TFo DK1 = TFo{S02.a, S13.a};
static constexpr TFo DK2 = TFo{S02.b, S13.b};
#endif

__device__ __forceinline__ void dtf(unsigned k1, unsigned k2, unsigned x0, unsigned x1,
                                    unsigned& o0, unsigned& o1) {
  unsigned ks2 = k1 ^ k2 ^ 0x1BD11BDAu;
#define TFR(r) { x0 += x1; x1 = (x1<<r)|(x1>>(32-r)); x1 ^= x0; }
  x0 += k1; x1 += k2;
  TFR(13) TFR(15) TFR(26) TFR(6)  x0 += k2;  x1 += ks2 + 1u;
  TFR(17) TFR(29) TFR(16) TFR(24) x0 += ks2; x1 += k1 + 2u;
  TFR(13) TFR(15) TFR(26) TFR(6)  x0 += k1;  x1 += k2 + 3u;
  TFR(17) TFR(29) TFR(16) TFR(24) x0 += k2;  x1 += ks2 + 4u;
  TFR(13) TFR(15) TFR(26) TFR(6)  x0 += ks2; x1 += k1 + 5u;
#undef TFR
  o0 = x0; o1 = x1;
}

// keep iff uniform(bits) < 0.5  <=>  top bit of bits == 0
__device__ __forceinline__ bool keepmask(unsigned ka, unsigned kb, unsigned j) {
#if TF_PARTITIONABLE
  unsigned o0, o1; dtf(ka, kb, 0u, j, o0, o1);
  return ((o0 ^ o1) >> 31) == 0u;
#else
  const unsigned H = 4202496u;  // (513*64*256)/2
  unsigned o0, o1;
  if (j < H) { dtf(ka, kb, j, j + H, o0, o1); return (o0 >> 31) == 0u; }
  else       { dtf(ka, kb, j - H, j, o0, o1); return (o1 >> 31) == 0u; }
#endif
}

// ---------------- dtype helpers ----------------
__device__ __forceinline__ float ldbf(const unsigned short* p, long i) {
  return __uint_as_float(((unsigned)p[i]) << 16);
}
__device__ __forceinline__ void store_out(void* out, long i, float v, int bf) {
  if (bf) {
    unsigned x = __float_as_uint(v);
    unsigned r = (x + 0x7fffu + ((x >> 16) & 1u)) >> 16;  // RNE
    ((unsigned short*)out)[i] = (unsigned short)r;
  } else ((float*)out)[i] = v;
}
__device__ __forceinline__ float st_load(const float* p, long i) { return p[i]; }
__device__ __forceinline__ float st_load(const unsigned short* p, long i) { return ldbf(p, i); }
__device__ __forceinline__ void st_store(float* p, long i, float v) { p[i] = v; }
__device__ __forceinline__ void st_store(unsigned short* p, long i, float v) {
  unsigned x = __float_as_uint(v);
  p[i] = (unsigned short)((x + 0x7fffu + ((x >> 16) & 1u)) >> 16);
}
__device__ __forceinline__ float sigm(float x) { return 1.f / (1.f + expf(-x)); }

// ---------------- pointer pack ----------------
struct Ptrs {
  const float *Wp1,*Wp2,*Wai,*Wah,*bai,*bah,*Wg1,*bg1,*Wg2,*Wdi,*Wdh,*bdi,*bdh,*Wpr,*bpr;
  float *pre,*Patt,*Pdec,*ah,*ac,*dh,*dc,*ctx,*mean;
  void *dh_all,*ctx_all;
  const void *mem,*din; const int *mlen; const int *flag; void *out;
};

// ---------------- utility kernels ----------------
__global__ __launch_bounds__(256) void k_detect(const void* mem, int* flag) {
  __shared__ int cnt;
  int tid = threadIdx.x;
  if (tid == 0) cnt = 0;
  __syncthreads();
  const unsigned short* p = (const unsigned short*)mem;
  int local = 0;
  for (int i = tid; i < 1024; i += 256) {
    float f = ldbf(p, 2L * i);            // even 16-bit halves
    if (f == f && fabsf(f) > 0.0009f && fabsf(f) < 16.f) local++;
  }
  atomicAdd(&cnt, local);
  __syncthreads();
  if (tid == 0) flag[0] = (cnt > 512) ? 1 : 0;
}

__global__ __launch_bounds__(256) void k_convert(const void* src, float* dst, long n, const int* flag) {
  int bf = *flag;
  long i0 = (long)blockIdx.x * 256 + threadIdx.x, stp = (long)gridDim.x * 256;
  if (bf) { const unsigned short* s = (const unsigned short*)src;
            for (long i = i0; i < n; i += stp) dst[i] = ldbf(s, i); }
  else    { const float* s = (const float*)src;
            for (long i = i0; i < n; i += stp) dst[i] = s[i]; }
}

__global__ __launch_bounds__(256) void k_zero_f32(float* p, long n) {
  for (long i = (long)blockIdx.x * 256 + threadIdx.x; i < n; i += (long)gridDim.x * 256) p[i] = 0.f;
}

__global__ __launch_bounds__(256) void k_zero_aligns(void* out, const int* flag) {
  int bf = *flag;
  unsigned* p; long n;
  if (bf) { p = (unsigned*)out + (ALIGNS_OFF >> 1); n = ((long)Bn*Tn*Ln) >> 1; }
  else    { p = (unsigned*)out + ALIGNS_OFF;        n = (long)Bn*Tn*Ln; }
  for (long i = (long)blockIdx.x * 256 + threadIdx.x; i < n; i += (long)gridDim.x * 256) p[i] = 0u;
}

// ---------------- prenet (fused GEMM1+mask1+GEMM2+mask2) ----------------
// grid = Tn*2 blocks (t, half-of-batch of 32), 256 threads.
__global__ __launch_bounds__(256) void k_prenet(Ptrs P, unsigned k1a, unsigned k1b,
                                                unsigned k2a, unsigned k2b) {
  __shared__ __align__(16) float x_s[32 * 17];     // phase1 input chunk
  __shared__ __align__(16) float W_s[16 * 256];    // W chunk (both phases)
  __shared__ __align__(16) float h1_s[32 * 258];   // masked h1
  int bid = blockIdx.x, tid = threadIdx.x;
  int t = bid >> 1, half = bid & 1;
  int bf = *P.flag;
  int tc = tid & 63, tr = tid >> 6;
  int p0 = tc * 4, bl0 = tr * 8;
  float acc[8][4];
#pragma unroll
  for (int i = 0; i < 8; ++i) { acc[i][0]=0; acc[i][1]=0; acc[i][2]=0; acc[i][3]=0; }

  // phase 1: h1 = x @ W_pre1, K = 512 in 32 chunks of 16
  for (int kc = 0; kc < 32; ++kc) {
    __syncthreads();
    for (int i = tid; i < 32 * 16; i += 256) {
      int bl = i >> 4, kk = i & 15;
      int s = kc * 16 + kk;
      float v = 0.f;
      if (t > 0) {
        long idx = ((long)(half * 32 + bl) * Sn + s) * Tn + (t - 1);
        v = bf ? ldbf((const unsigned short*)P.din, idx) : ((const float*)P.din)[idx];
      }
      x_s[bl * 17 + kk] = v;
    }
    for (int i = tid; i < 16 * 256; i += 256) {
      int kk = i >> 8, p = i & 255;
      W_s[kk * 256 + p] = P.Wp1[(long)(kc * 16 + kk) * 256 + p];
    }
    __syncthreads();
    for (int kk = 0; kk < 16; ++kk) {
      float4 w = *(const float4*)(W_s + kk * 256 + p0);
#pragma unroll
      for (int i = 0; i < 8; ++i) {
        float x = x_s[(bl0 + i) * 17 + kk];
        acc[i][0] += x * w.x; acc[i][1] += x * w.y; acc[i][2] += x * w.z; acc[i][3] += x * w.w;
      }
    }
  }
  // relu + dropout mask1 (*2), write h1 to LDS
#pragma unroll
  for (int i = 0; i < 8; ++i)
#pragma unroll
    for (int j = 0; j < 4; ++j) {
      int bl = bl0 + i, p = p0 + j, bg = half * 32 + bl;
      float v = fmaxf(acc[i][j], 0.f);
      unsigned ft = (unsigned)(((long)t * 64 + bg) * 256 + p);
      v = keepmask(k1a, k1b, ft) ? 2.f * v : 0.f;
      h1_s[bl * 258 + p] = v;
      acc[i][j] = 0.f;
    }
  __syncthreads();
  // phase 2: pre = h1 @ W_pre2, K = 256 in 16 chunks of 16
  for (int kc = 0; kc < 16; ++kc) {
    __syncthreads();
    for (int i = tid; i < 16 * 256; i += 256) {
      int kk = i >> 8, p = i & 255;
      W_s[kk * 256 + p] = P.Wp2[(long)(kc * 16 + kk) * 256 + p];
    }
    __syncthreads();
    for (int kk = 0; kk < 16; ++kk) {
      float4 w = *(const float4*)(W_s + kk * 256 + p0);
      int s = kc * 16 + kk;
#pragma unroll
      for (int i = 0; i < 8; ++i) {
        float x = h1_s[(bl0 + i) * 258 + s];
        acc[i][0] += x * w.x; acc[i][1] += x * w.y; acc[i][2] += x * w.z; acc[i][3] += x * w.w;
      }
    }
  }
#pragma unroll
  for (int i = 0; i < 8; ++i)
#pragma unroll
    for (int j = 0; j < 4; ++j) {
      int bg = half * 32 + bl0 + i, p = p0 + j;
      float v = fmaxf(acc[i][j], 0.f);
      unsigned ft = (unsigned)(((long)t * 64 + bg) * 256 + p);
      v = keepmask(k2a, k2b, ft) ? 2.f * v : 0.f;
      P.pre[((long)t * 64 + bg) * 256 + p] = v;
    }
}

// ---------------- step kernel A: att gates GEMM + deferred dec pointwise ----------------
// blocks 0..255: att gate partials for step t (if t < Tn): kc = bid>>5 (8 x 224), ct = bid&31 (32 x 128 cols)
// blocks 256..287: dec LSTM pointwise for step t-1 (if t > 0)
template<typename ST>
__global__ __launch_bounds__(256) void k_stepA(Ptrs P, int t) {
  int bid = blockIdx.x, tid = threadIdx.x;
  if (bid < 256) {
    if (t >= Tn) return;
    __shared__ __align__(16) float in_s[64][ACK + 1];
    int kc = bid >> 5, ct = bid & 31;
    for (int i = tid; i < 64 * ACK; i += 256) {
      int b = i / ACK, kk = i - b * ACK;
      int k = kc * ACK + kk;
      float v;
      if (k < Pn)            v = P.pre[((long)t * 64 + b) * Pn + k];
      else if (k < Pn + En)  v = P.ctx[b * En + (k - Pn)];
      else                   v = P.ah[b * An + (k - Pn - En)];
      in_s[b][kk] = v;
    }
    __syncthreads();
    int tc = tid & 31, tr = tid >> 5;
    int c0 = ct * 128 + tc * 4, b0 = tr * 8;
    float acc[8][4];
#pragma unroll
    for (int i = 0; i < 8; ++i) { acc[i][0]=0; acc[i][1]=0; acc[i][2]=0; acc[i][3]=0; }
    for (int kk = 0; kk < ACK; ++kk) {
      int k = kc * ACK + kk;
      const float* wrow = (k < Pn + En) ? (P.Wai + (long)k * G4A)
                                        : (P.Wah + (long)(k - Pn - En) * G4A);
      float4 w = *(const float4*)(wrow + c0);
#pragma unroll
      for (int i = 0; i < 8; ++i) {
        float x = in_s[b0 + i][kk];
        acc[i][0] += x * w.x; acc[i][1] += x * w.y; acc[i][2] += x * w.z; acc[i][3] += x * w.w;
      }
    }
#pragma unroll
    for (int i = 0; i < 8; ++i) {
      float4 v = make_float4(acc[i][0], acc[i][1], acc[i][2], acc[i][3]);
      *(float4*)(P.Patt + ((long)kc * 64 + b0 + i) * G4A + c0) = v;
    }
  } else {
    if (t == 0) return;
    int bb = bid - 256;                 // 0..31 -> 2 batch rows each
    ST* dh_all = (ST*)P.dh_all;
    for (int i = tid; i < 2048; i += 256) {
      int b = bb * 2 + (i >> 10), u = i & 1023;
      float gi = P.bdi[u]        + P.bdh[u];
      float gf = P.bdi[u + 1024] + P.bdh[u + 1024];
      float gg = P.bdi[u + 2048] + P.bdh[u + 2048];
      float go = P.bdi[u + 3072] + P.bdh[u + 3072];
      for (int kc = 0; kc < DCH; ++kc) {
        const float* pd = P.Pdec + ((long)kc * 64 + b) * G4A;
        gi += pd[u]; gf += pd[u + 1024]; gg += pd[u + 2048]; go += pd[u + 3072];
      }
      float ii = sigm(gi), ff = sigm(gf), oo = sigm(go);
      float cc = ff * P.dc[b * 1024 + u] + ii * tanhf(gg);
      float hh = oo * tanhf(cc);
      P.dc[b * 1024 + u] = cc;
      P.dh[b * 1024 + u] = hh;
      st_store(dh_all, ((long)(t - 1) * 64 + b) * 1024 + u, hh);
    }
  }
}

// ---------------- step kernel B: att pointwise + GMM + alpha + ctx ----------------
template<typename ST>
__global__ __launch_bounds__(256) void k_stepB(Ptrs P, int t) {
  int b = blockIdx.x, tid = threadIdx.x;
  __shared__ float ah_s[1024];
  __shared__ float tanh_s[128];
  __shared__ float bc_s[2];
  __shared__ float alpha_s[176];
  int bf = *P.flag;
  // attention LSTM pointwise
  for (int u = tid; u < 1024; u += 256) {
    float gi = P.bai[u]        + P.bah[u];
    float gf = P.bai[u + 1024] + P.bah[u + 1024];
    float gg = P.bai[u + 2048] + P.bah[u + 2048];
    float go = P.bai[u + 3072] + P.bah[u + 3072];
    for (int kc = 0; kc < ACH; ++kc) {
      const float* pa = P.Patt + ((long)kc * 64 + b) * G4A;
      gi += pa[u]; gf += pa[u + 1024]; gg += pa[u + 2048]; go += pa[u + 3072];
    }
    float ii = sigm(gi), ff = sigm(gf), oo = sigm(go);
    float cc = ff * P.ac[b * 1024 + u] + ii * tanhf(gg);
    float hh = oo * tanhf(cc);
    P.ac[b * 1024 + u] = cc;
    P.ah[b * 1024 + u] = hh;
    ah_s[u] = hh;
  }
  __syncthreads();
  // GMM hidden: tanh(ah @ W_g1 + b_g1)
  if (tid < 128) {
    float a0 = 0, a1 = 0, a2 = 0, a3 = 0;
    for (int u = 0; u < 1024; u += 4) {
      a0 += ah_s[u    ] * P.Wg1[(long)(u    ) * 128 + tid];
      a1 += ah_s[u + 1] * P.Wg1[(long)(u + 1) * 128 + tid];
      a2 += ah_s[u + 2] * P.Wg1[(long)(u + 2) * 128 + tid];
      a3 += ah_s[u + 3] * P.Wg1[(long)(u + 3) * 128 + tid];
    }
    tanh_s[tid] = tanhf(a0 + a1 + a2 + a3 + P.bg1[tid]);
  }
  __syncthreads();
  if (tid == 0) {
    float h0 = 0.f, h1 = 0.f;
    for (int j = 0; j < 128; ++j) {
      float tv = tanh_s[j];
      h0 += tv * P.Wg2[2 * j];
      h1 += tv * P.Wg2[2 * j + 1];
    }
    float m  = P.mean[b] + expf(h0) * 8.f;
    float sc = expf(h1) * 8.f;
    P.mean[b] = m;
    long pidx = PARAMS_OFF + ((long)b * Tn + t) * 2;
    store_out(P.out, pidx, h0, bf);
    store_out(P.out, pidx + 1, h1, bf);
    bc_s[0] = m; bc_s[1] = sc;
  }
  __syncthreads();
  float m = bc_s[0], sc = bc_s[1];
  int len = P.mlen[b];
  int ci = (int)floorf(fminf(m, 100000.f));
  int l0 = ci - 80; if (l0 < 0) l0 = 0;
  int l1 = ci + 81; if (l1 > len) l1 = len;   // len <= L, also applies pad mask
  float inv2 = 0.5f / (sc * sc);
  float invZ = 1.f / (2.50662827463100050242f * sc);  // 1/sqrt(2*pi*sc^2)
  for (int l = l0 + tid; l < l1; l += 256) {
    float d = (float)l - m;
    float al = expf(-d * d * inv2) * invZ;
    alpha_s[l - l0] = al;
    store_out(P.out, ALIGNS_OFF + ((long)b * Tn + t) * Ln + l, al, bf);
  }
  __syncthreads();
  int nl = l1 - l0;
  ST* ctx_all = (ST*)P.ctx_all;
  if (bf) {
    const unsigned short* mem = (const unsigned short*)P.mem;
    for (int e = tid; e < En; e += 256) {
      float s = 0.f;
      for (int l = 0; l < nl; ++l)
        s += alpha_s[l] * ldbf(mem, ((long)b * Ln + (l0 + l)) * En + e);
      P.ctx[b * En + e] = s;
      st_store(ctx_all, ((long)t * 64 + b) * En + e, s);
    }
  } else {
    const float* mem = (const float*)P.mem;
    for (int e = tid; e < En; e += 256) {
      float s = 0.f;
      for (int l = 0; l < nl; ++l)
        s += alpha_s[l] * mem[((long)b * Ln + (l0 + l)) * En + e];
      P.ctx[b * En + e] = s;
      st_store(ctx_all, ((long)t * 64 + b) * En + e, s);
    }
  }
}

// ---------------- step kernel C: dec gates GEMM partials ----------------
// grid = 512: kc = bid>>5 (16 x 160), ct = bid&31 (32 x 128 cols)
__global__ __launch_bounds__(256) void k_stepC(Ptrs P, int t) {
  __shared__ __align__(16) float in_s[64][DCK + 1];
  int bid = blockIdx.x, tid = threadIdx.x;
  int kc = bid >> 5, ct = bid & 31;
  for (int i = tid; i < 64 * DCK; i += 256) {
    int b = i / DCK, kk = i - b * DCK;
    int k = kc * DCK + kk;
    float v;
    if (k < An)            v = P.ah[b * An + k];
    else if (k < An + En)  v = P.ctx[b * En + (k - An)];
    else                   v = P.dh[b * Dn + (k - An - En)];
    in_s[b][kk] = v;
  }
  __syncthreads();
  int tc = tid & 31, tr = tid >> 5;
  int c0 = ct * 128 + tc * 4, b0 = tr * 8;
  float acc[8][4];
#pragma unroll
  for (int i = 0; i < 8; ++i) { acc[i][0]=0; acc[i][1]=0; acc[i][2]=0; acc[i][3]=0; }
  for (int kk = 0; kk < DCK; ++kk) {
    int k = kc * DCK + kk;
    const float* wrow = (k < An + En) ? (P.Wdi + (long)k * G4A)
                                      : (P.Wdh + (long)(k - An - En) * G4A);
    float4 w = *(const float4*)(wrow + c0);
#pragma unroll
    for (int i = 0; i < 8; ++i) {
      float x = in_s[b0 + i][kk];
      acc[i][0] += x * w.x; acc[i][1] += x * w.y; acc[i][2] += x * w.z; acc[i][3] += x * w.w;
    }
  }
#pragma unroll
  for (int i = 0; i < 8; ++i) {
    float4 v = make_float4(acc[i][0], acc[i][1], acc[i][2], acc[i][3]);
    *(float4*)(P.Pdec + ((long)kc * 64 + b0 + i) * G4A + c0) = v;
  }
}

// ---------------- final projection: logits = [dh, ctx] @ W_proj + b ----------------
template<typename ST>
__global__ __launch_bounds__(256) void k_proj(Ptrs P) {
  __shared__ __align__(16) float A_s[64][65];
  __shared__ __align__(16) float W_s[64 * 160];
  int t = blockIdx.x, tid = threadIdx.x;
  int bf = *P.flag;
  const ST* dh_all = (const ST*)P.dh_all;
  const ST* ctx_all = (const ST*)P.ctx_all;
  int tc = tid & 15, tr = tid >> 4;
  int c0 = tc * 10, b0 = tr * 4;
  float acc[4][10];
#pragma unroll
  for (int i = 0; i < 4; ++i)
#pragma unroll
    for (int j = 0; j < 10; ++j) acc[i][j] = 0.f;
  for (int k0 = 0; k0 < KPROJ; k0 += 64) {
    __syncthreads();
    for (int i = tid; i < 64 * 64; i += 256) {
      int b = i >> 6, kk = i & 63;
      int k = k0 + kk;
      float v = (k < Dn) ? st_load(dh_all, ((long)t * 64 + b) * Dn + k)
                         : st_load(ctx_all, ((long)t * 64 + b) * En + (k - Dn));
      A_s[b][kk] = v;
    }
    for (int i = tid; i < 64 * 160; i += 256) {
      int kk = i / 160, c = i - kk * 160;
      W_s[kk * 160 + c] = (c < Vn) ? P.Wpr[(long)(k0 + kk) * Vn + c] : 0.f;
    }
    __syncthreads();
    for (int kk = 0; kk < 64; ++kk) {
      float xs[4];
#pragma unroll
      for (int i = 0; i < 4; ++i) xs[i] = A_s[b0 + i][kk];
#pragma unroll
      for (int j = 0; j < 10; ++j) {
        float w = W_s[kk * 160 + c0 + j];
#pragma unroll
        for (int i = 0; i < 4; ++i) acc[i][j] += xs[i] * w;
      }
    }
  }
#pragma unroll
  for (int i = 0; i < 4; ++i)
#pragma unroll
    for (int j = 0; j < 10; ++j) {
      int c = c0 + j;
      if (c < Vn) {
        int b = b0 + i;
        store_out(P.out, LOGITS_OFF + ((long)b * Tn + t) * Vn + c, acc[i][j] + P.bpr[c], bf);
      }
    }
}

// ---------------- host ----------------
template<typename ST>
static void run_pipeline(const Ptrs& P, hipStream_t stream) {
  k_prenet<<<Tn * 2, 256, 0, stream>>>(P, DK1.a, DK1.b, DK2.a, DK2.b);
  for (int t = 0; t <= Tn; ++t) {
    k_stepA<ST><<<288, 256, 0, stream>>>(P, t);
    if (t < Tn) {
      k_stepB<ST><<<64, 256, 0, stream>>>(P, t);
      k_stepC<<<512, 256, 0, stream>>>(P, t);
    }
  }
  k_proj<ST><<<Tn, 256, 0, stream>>>(P);
}

extern "C" void kernel_launch(void* const* d_in, const int* in_sizes, int n_in,
                              void* d_out, int out_size, void* d_ws, size_t ws_size,
                              hipStream_t stream) {
  (void)in_sizes; (void)n_in; (void)out_size;
  char* base = (char*)d_ws;
  int* flag = (int*)base;
  size_t off = 256;
  auto allocf = [&](size_t n) -> float* {
    float* p = (float*)(base + off);
    off += ((n * 4 + 255) / 256) * 256;
    return p;
  };
  float* Wp1 = allocf(131072);
  float* Wp2 = allocf(65536);
  float* Wai = allocf(3145728);
  float* Wah = allocf(4194304);
  float* bai = allocf(4096);
  float* bah = allocf(4096);
  float* Wg1 = allocf(131072);
  float* bg1 = allocf(128);
  float* Wg2 = allocf(256);
  float* Wdi = allocf(6291456);
  float* Wdh = allocf(4194304);
  float* bdi = allocf(4096);
  float* bdh = allocf(4096);
  float* Wpr = allocf(227328);
  float* bpr = allocf(148);
  float* pre  = allocf((size_t)Tn * 64 * Pn);           // 8.4M
  float* Patt = allocf((size_t)ACH * 64 * G4A);         // 2.1M
  float* Pdec = allocf((size_t)DCH * 64 * G4A);         // 4.2M
  float* ah = allocf(65536);
  float* ac = allocf(65536);
  float* dh = allocf(65536);
  float* dc = allocf(65536);
  float* ctx = allocf(32768);
  float* mean = allocf(64);
  size_t fixed = off;
  size_t nDH = (size_t)Tn * 64 * Dn, nCX = (size_t)Tn * 64 * En;
  bool f32tier = (fixed + (nDH + nCX) * 4 <= ws_size);
  bool b16tier = (fixed + (nDH + nCX) * 2 <= ws_size);
  if (!f32tier && !b16tier) return;  // ws too small; fail visibly

  Ptrs P;
  P.Wp1=Wp1; P.Wp2=Wp2; P.Wai=Wai; P.Wah=Wah; P.bai=bai; P.bah=bah;
  P.Wg1=Wg1; P.bg1=bg1; P.Wg2=Wg2; P.Wdi=Wdi; P.Wdh=Wdh; P.bdi=bdi; P.bdh=bdh;
  P.Wpr=Wpr; P.bpr=bpr;
  P.pre=pre; P.Patt=Patt; P.Pdec=Pdec; P.ah=ah; P.ac=ac; P.dh=dh; P.dc=dc;
  P.ctx=ctx; P.mean=mean;
  size_t esz = f32tier ? 4 : 2;
  P.dh_all  = base + fixed;
  P.ctx_all = base + fixed + nDH * esz;
  P.mem = d_in[0]; P.din = d_in[1]; P.mlen = (const int*)d_in[2];
  P.flag = flag; P.out = d_out;

  k_detect<<<1, 256, 0, stream>>>(d_in[0], flag);

  struct CV { const void* s; float* d; long n; };
  const CV cv[15] = {
    {d_in[3], Wp1, 131072}, {d_in[4], Wp2, 65536}, {d_in[5], Wai, 3145728},
    {d_in[6], Wah, 4194304}, {d_in[7], bai, 4096}, {d_in[8], bah, 4096},
    {d_in[9], Wg1, 131072}, {d_in[10], bg1, 128}, {d_in[11], Wg2, 256},
    {d_in[12], Wdi, 6291456}, {d_in[13], Wdh, 4194304}, {d_in[14], bdi, 4096},
    {d_in[15], bdh, 4096}, {d_in[16], Wpr, 227328}, {d_in[17], bpr, 148},
  };
  for (int i = 0; i < 15; ++i) {
    long g = (cv[i].n + 255) / 256; if (g > 1024) g = 1024;
    k_convert<<<(int)g, 256, 0, stream>>>(cv[i].s, cv[i].d, cv[i].n, flag);
  }
  k_zero_f32<<<512, 256, 0, stream>>>(ah, 65536L * 4 + 32768 + 64);  // states are contiguous
  k_zero_aligns<<<2048, 256, 0, stream>>>(d_out, flag);

  if (f32tier) run_pipeline<float>(P, stream);
  else         run_pipeline<unsigned short>(P, stream);
}

// Round 2
// 39142.493 us; speedup vs baseline: 1.7943x; 1.7943x over previous
//
#include <hip/hip_runtime.h>
#include <math.h>

// ---------------- config ----------------
#define TF_PARTITIONABLE 1   // jax threefry_partitionable (default True since jax 0.4.36)

static constexpr int Bn=64, Ln=512, En=512, Tn=512, Sn=512, Pn=256, An=1024, Dn=1024, Gn=128, Vn=148;
static constexpr int G4A = 4096;            // 4*A == 4*D
static constexpr int KPROJ = Dn + En;       // 1536
static constexpr int ACH = 16, ACK = 112;   // att gates K=1792 = 16*112
static constexpr int DCH = 16, DCK = 160;   // dec gates K=2560 = 16*160
static constexpr long LOGITS_OFF = 0;
static constexpr long ALIGNS_OFF = (long)Bn*Tn*Vn;               // 4,849,664
static constexpr long PARAMS_OFF = ALIGNS_OFF + (long)Bn*Tn*Ln;  // 21,626,880

// ---------------- threefry2x32 (jax-exact) ----------------
struct TFo { unsigned a, b; };
static constexpr TFo htf(unsigned k1, unsigned k2, unsigned x0, unsigned x1) {
  unsigned ks2 = k1 ^ k2 ^ 0x1BD11BDAu;
  unsigned ks[3] = {k1, k2, ks2};
  const unsigned ra[4] = {13u,15u,26u,6u}, rb[4] = {17u,29u,16u,24u};
  x0 += k1; x1 += k2;
  for (int g = 0; g < 5; ++g) {
    const unsigned* r = (g % 2 == 0) ? ra : rb;
    for (int i = 0; i < 4; ++i) { x0 += x1; x1 = (x1 << r[i]) | (x1 >> (32u - r[i])); x1 ^= x0; }
    x0 += ks[(g+1)%3]; x1 += ks[(g+2)%3] + (unsigned)(g+1);
  }
  return TFo{x0, x1};
}
#if TF_PARTITIONABLE
static constexpr TFo DK1 = htf(0u,42u,0u,0u);   // split(key(42))[0]
static constexpr TFo DK2 = htf(0u,42u,0u,1u);   // split(key(42))[1]
#else
static constexpr TFo S02 = htf(0u,42u,0u,2u);
static constexpr TFo S13 = htf(0u,42u,1u,3u);
static constexpr TFo DK1 = TFo{S02.a, S13.a};
static constexpr TFo DK2 = TFo{S02.b, S13.b};
#endif

__device__ __forceinline__ void dtf(unsigned k1, unsigned k2, unsigned x0, unsigned x1,
                                    unsigned& o0, unsigned& o1) {
  unsigned ks2 = k1 ^ k2 ^ 0x1BD11BDAu;
#define TFR(r) { x0 += x1; x1 = (x1<<r)|(x1>>(32-r)); x1 ^= x0; }
  x0 += k1; x1 += k2;
  TFR(13) TFR(15) TFR(26) TFR(6)  x0 += k2;  x1 += ks2 + 1u;
  TFR(17) TFR(29) TFR(16) TFR(24) x0 += ks2; x1 += k1 + 2u;
  TFR(13) TFR(15) TFR(26) TFR(6)  x0 += k1;  x1 += k2 + 3u;
  TFR(17) TFR(29) TFR(16) TFR(24) x0 += k2;  x1 += ks2 + 4u;
  TFR(13) TFR(15) TFR(26) TFR(6)  x0 += ks2; x1 += k1 + 5u;
#undef TFR
  o0 = x0; o1 = x1;
}

__device__ __forceinline__ bool keepmask(unsigned ka, unsigned kb, unsigned j) {
#if TF_PARTITIONABLE
  unsigned o0, o1; dtf(ka, kb, 0u, j, o0, o1);
  return ((o0 ^ o1) >> 31) == 0u;
#else
  const unsigned H = 4202496u;  // (513*64*256)/2
  unsigned o0, o1;
  if (j < H) { dtf(ka, kb, j, j + H, o0, o1); return (o0 >> 31) == 0u; }
  else       { dtf(ka, kb, j - H, j, o0, o1); return (o1 >> 31) == 0u; }
#endif
}

// ---------------- dtype helpers ----------------
__device__ __forceinline__ float ldbf(const unsigned short* p, long i) {
  return __uint_as_float(((unsigned)p[i]) << 16);
}
__device__ __forceinline__ void store_out(void* out, long i, float v, int bf) {
  if (bf) {
    unsigned x = __float_as_uint(v);
    unsigned r = (x + 0x7fffu + ((x >> 16) & 1u)) >> 16;  // RNE
    ((unsigned short*)out)[i] = (unsigned short)r;
  } else ((float*)out)[i] = v;
}
__device__ __forceinline__ float st_load(const float* p, long i) { return p[i]; }
__device__ __forceinline__ float st_load(const unsigned short* p, long i) { return ldbf(p, i); }
__device__ __forceinline__ void st_store(float* p, long i, float v) { p[i] = v; }
__device__ __forceinline__ void st_store(unsigned short* p, long i, float v) {
  unsigned x = __float_as_uint(v);
  p[i] = (unsigned short)((x + 0x7fffu + ((x >> 16) & 1u)) >> 16);
}
__device__ __forceinline__ float sigm(float x) { return 1.f / (1.f + expf(-x)); }

// ---------------- pointer pack ----------------
struct Ptrs {
  const float *Wp1,*Wp2,*Wai,*Wah,*bai,*bah,*Wg1,*bg1,*Wg2,*Wdi,*Wdh,*bdi,*bdh,*Wpr,*bpr;
  float *pre,*Patt,*Pdec,*ah,*ac,*dh,*dc,*ctx,*mean;
  void *dh_all,*ctx_all;
  const void *mem,*din; const int *mlen; const int *flag; void *out;
};

// ---------------- utility kernels ----------------
__global__ __launch_bounds__(256) void k_detect(const void* mem, int* flag) {
  __shared__ int cnt;
  int tid = threadIdx.x;
  if (tid == 0) cnt = 0;
  __syncthreads();
  const unsigned short* p = (const unsigned short*)mem;
  int local = 0;
  for (int i = tid; i < 1024; i += 256) {
    float f = ldbf(p, 2L * i);
    if (f == f && fabsf(f) > 0.0009f && fabsf(f) < 16.f) local++;
  }
  atomicAdd(&cnt, local);
  __syncthreads();
  if (tid == 0) flag[0] = (cnt > 512) ? 1 : 0;
}

__global__ __launch_bounds__(256) void k_convert(const void* src, float* dst, long n, const int* flag) {
  int bf = *flag;
  long i0 = (long)blockIdx.x * 256 + threadIdx.x, stp = (long)gridDim.x * 256;
  if (bf) { const unsigned short* s = (const unsigned short*)src;
            for (long i = i0; i < n; i += stp) dst[i] = ldbf(s, i); }
  else    { const float* s = (const float*)src;
            for (long i = i0; i < n; i += stp) dst[i] = s[i]; }
}

__global__ __launch_bounds__(256) void k_zero_f32(float* p, long n) {
  for (long i = (long)blockIdx.x * 256 + threadIdx.x; i < n; i += (long)gridDim.x * 256) p[i] = 0.f;
}

__global__ __launch_bounds__(256) void k_zero_aligns(void* out, const int* flag) {
  int bf = *flag;
  unsigned* p; long n;
  if (bf) { p = (unsigned*)out + (ALIGNS_OFF >> 1); n = ((long)Bn*Tn*Ln) >> 1; }
  else    { p = (unsigned*)out + ALIGNS_OFF;        n = (long)Bn*Tn*Ln; }
  for (long i = (long)blockIdx.x * 256 + threadIdx.x; i < n; i += (long)gridDim.x * 256) p[i] = 0u;
}

// ---------------- prenet (fused GEMM1+mask1+GEMM2+mask2) ----------------
__global__ __launch_bounds__(256) void k_prenet(Ptrs P, unsigned k1a, unsigned k1b,
                                                unsigned k2a, unsigned k2b) {
  __shared__ __align__(16) float x_s[32 * 17];
  __shared__ __align__(16) float W_s[16 * 256];
  __shared__ __align__(16) float h1_s[32 * 258];
  int bid = blockIdx.x, tid = threadIdx.x;
  int t = bid >> 1, half = bid & 1;
  int bf = *P.flag;
  int tc = tid & 63, tr = tid >> 6;
  int p0 = tc * 4, bl0 = tr * 8;
  float acc[8][4];
#pragma unroll
  for (int i = 0; i < 8; ++i) { acc[i][0]=0; acc[i][1]=0; acc[i][2]=0; acc[i][3]=0; }

  for (int kc = 0; kc < 32; ++kc) {
    __syncthreads();
    for (int i = tid; i < 32 * 16; i += 256) {
      int bl = i >> 4, kk = i & 15;
      int s = kc * 16 + kk;
      float v = 0.f;
      if (t > 0) {
        long idx = ((long)(half * 32 + bl) * Sn + s) * Tn + (t - 1);
        v = bf ? ldbf((const unsigned short*)P.din, idx) : ((const float*)P.din)[idx];
      }
      x_s[bl * 17 + kk] = v;
    }
    for (int i = tid; i < 16 * 256; i += 256) {
      int kk = i >> 8, p = i & 255;
      W_s[kk * 256 + p] = P.Wp1[(long)(kc * 16 + kk) * 256 + p];
    }
    __syncthreads();
    for (int kk = 0; kk < 16; ++kk) {
      float4 w = *(const float4*)(W_s + kk * 256 + p0);
#pragma unroll
      for (int i = 0; i < 8; ++i) {
        float x = x_s[(bl0 + i) * 17 + kk];
        acc[i][0] += x * w.x; acc[i][1] += x * w.y; acc[i][2] += x * w.z; acc[i][3] += x * w.w;
      }
    }
  }
#pragma unroll
  for (int i = 0; i < 8; ++i)
#pragma unroll
    for (int j = 0; j < 4; ++j) {
      int bl = bl0 + i, p = p0 + j, bg = half * 32 + bl;
      float v = fmaxf(acc[i][j], 0.f);
      unsigned ft = (unsigned)(((long)t * 64 + bg) * 256 + p);
      v = keepmask(k1a, k1b, ft) ? 2.f * v : 0.f;
      h1_s[bl * 258 + p] = v;
      acc[i][j] = 0.f;
    }
  __syncthreads();
  for (int kc = 0; kc < 16; ++kc) {
    __syncthreads();
    for (int i = tid; i < 16 * 256; i += 256) {
      int kk = i >> 8, p = i & 255;
      W_s[kk * 256 + p] = P.Wp2[(long)(kc * 16 + kk) * 256 + p];
    }
    __syncthreads();
    for (int kk = 0; kk < 16; ++kk) {
      float4 w = *(const float4*)(W_s + kk * 256 + p0);
      int s = kc * 16 + kk;
#pragma unroll
      for (int i = 0; i < 8; ++i) {
        float x = h1_s[(bl0 + i) * 258 + s];
        acc[i][0] += x * w.x; acc[i][1] += x * w.y; acc[i][2] += x * w.z; acc[i][3] += x * w.w;
      }
    }
  }
#pragma unroll
  for (int i = 0; i < 8; ++i)
#pragma unroll
    for (int j = 0; j < 4; ++j) {
      int bg = half * 32 + bl0 + i, p = p0 + j;
      float v = fmaxf(acc[i][j], 0.f);
      unsigned ft = (unsigned)(((long)t * 64 + bg) * 256 + p);
      v = keepmask(k2a, k2b, ft) ? 2.f * v : 0.f;
      P.pre[((long)t * 64 + bg) * 256 + p] = v;
    }
}

// ---------------- K1: combined gate GEMMs ----------------
// blocks 0..511:   att gates for step t+1 (skip if t+1 >= Tn): kc=bid>>5 (16 x 112), ct=bid&31
// blocks 512..1023: dec gates for step t (skip if t < 0):      kc=(bid-512)>>5 (16 x 160), ct
// A-tile staged transposed in LDS: A_s[kk*68 + b]; weights streamed float4.
__global__ __launch_bounds__(256) void k_gemm(Ptrs P, int t) {
  __shared__ __align__(16) float A_s[DCK * 68];   // 160*68*4 = 43.5 KB (union; att uses 112 rows)
  int bid = blockIdx.x, tid = threadIdx.x;
  bool att = bid < 512;
  if (att) { if (t + 1 >= Tn) return; }
  else     { if (t < 0) return; }
  int lb = att ? bid : bid - 512;
  int kc = lb >> 5, ct = lb & 31;
  const int KL = att ? ACK : DCK;
  const int K0 = kc * KL;
  if (att) {
    int s = t + 1;
    for (int i = tid; i < 64 * ACK; i += 256) {
      int b = i / ACK, kk = i - b * ACK;
      int k = K0 + kk;
      float v;
      if (k < Pn)           v = P.pre[((long)s * 64 + b) * Pn + k];
      else if (k < Pn + En) v = P.ctx[b * En + (k - Pn)];
      else                  v = P.ah[b * An + (k - Pn - En)];
      A_s[kk * 68 + b] = v;
    }
  } else {
    for (int i = tid; i < 64 * DCK; i += 256) {
      int b = i / DCK, kk = i - b * DCK;
      int k = K0 + kk;
      float v;
      if (k < An)           v = P.ah[b * An + k];
      else if (k < An + En) v = P.ctx[b * En + (k - An)];
      else                  v = P.dh[b * Dn + (k - An - En)];
      A_s[kk * 68 + b] = v;
    }
  }
  __syncthreads();
  int tc = tid & 31, tr = tid >> 5;
  int c0 = ct * 128 + tc * 4, r0 = tr * 8;
  float acc[8][4];
#pragma unroll
  for (int i = 0; i < 8; ++i) { acc[i][0]=0; acc[i][1]=0; acc[i][2]=0; acc[i][3]=0; }
  const float* W0 = att ? P.Wai : P.Wdi;
  const float* W1 = att ? P.Wah : P.Wdh;
  const int split = att ? (Pn + En) : (An + En);
  float* Pout = (att ? P.Patt : P.Pdec) + (long)kc * 64 * G4A;
#pragma unroll 4
  for (int kk = 0; kk < KL; ++kk) {
    int k = K0 + kk;
    const float* wrow = (k < split) ? (W0 + (long)k * G4A) : (W1 + (long)(k - split) * G4A);
    float4 w = *(const float4*)(wrow + c0);
    const float* ar = A_s + kk * 68 + r0;
    float4 a0 = *(const float4*)(ar);
    float4 a1 = *(const float4*)(ar + 4);
    acc[0][0] += a0.x*w.x; acc[0][1] += a0.x*w.y; acc[0][2] += a0.x*w.z; acc[0][3] += a0.x*w.w;
    acc[1][0] += a0.y*w.x; acc[1][1] += a0.y*w.y; acc[1][2] += a0.y*w.z; acc[1][3] += a0.y*w.w;
    acc[2][0] += a0.z*w.x; acc[2][1] += a0.z*w.y; acc[2][2] += a0.z*w.z; acc[2][3] += a0.z*w.w;
    acc[3][0] += a0.w*w.x; acc[3][1] += a0.w*w.y; acc[3][2] += a0.w*w.z; acc[3][3] += a0.w*w.w;
    acc[4][0] += a1.x*w.x; acc[4][1] += a1.x*w.y; acc[4][2] += a1.x*w.z; acc[4][3] += a1.x*w.w;
    acc[5][0] += a1.y*w.x; acc[5][1] += a1.y*w.y; acc[5][2] += a1.y*w.z; acc[5][3] += a1.y*w.w;
    acc[6][0] += a1.z*w.x; acc[6][1] += a1.z*w.y; acc[6][2] += a1.z*w.z; acc[6][3] += a1.z*w.w;
    acc[7][0] += a1.w*w.x; acc[7][1] += a1.w*w.y; acc[7][2] += a1.w*w.z; acc[7][3] += a1.w*w.w;
  }
#pragma unroll
  for (int i = 0; i < 8; ++i) {
    *(float4*)(Pout + (long)(r0 + i) * G4A + c0) =
        make_float4(acc[i][0], acc[i][1], acc[i][2], acc[i][3]);
  }
}

// ---------------- K2: pointwise phase ----------------
// blocks 0..63:  att LSTM pointwise(t) + GMM + alpha + ctx (skip if t >= Tn)
// blocks 64..95: dec LSTM pointwise(t-1) (skip if t == 0)
template<typename ST>
__global__ __launch_bounds__(256) void k_point(Ptrs P, int t) {
  __shared__ float ah_s[1024];
  __shared__ float red_s[256];
  __shared__ float tanh_s[128];
  __shared__ float bc_s[2];
  __shared__ float alpha_s[176];
  int bid = blockIdx.x, tid = threadIdx.x;
  if (bid < 64) {
    if (t >= Tn) return;
    int b = bid;
    int bf = *P.flag;
    // attention LSTM pointwise (reduce ACH chunk partials)
    for (int u = tid; u < 1024; u += 256) {
      float gi = P.bai[u]        + P.bah[u];
      float gf = P.bai[u + 1024] + P.bah[u + 1024];
      float gg = P.bai[u + 2048] + P.bah[u + 2048];
      float go = P.bai[u + 3072] + P.bah[u + 3072];
      for (int kc = 0; kc < ACH; ++kc) {
        const float* pa = P.Patt + ((long)kc * 64 + b) * G4A;
        gi += pa[u]; gf += pa[u + 1024]; gg += pa[u + 2048]; go += pa[u + 3072];
      }
      float ii = sigm(gi), ff = sigm(gf), oo = sigm(go);
      float cc = ff * P.ac[b * 1024 + u] + ii * tanhf(gg);
      float hh = oo * tanhf(cc);
      P.ac[b * 1024 + u] = cc;
      P.ah[b * 1024 + u] = hh;
      ah_s[u] = hh;
    }
    __syncthreads();
    // GMM hidden: tanh(ah @ W_g1 + b_g1) — 2-stage reduction
    {
      int g = tid & 127, hf = tid >> 7;
      const float* w = P.Wg1 + g;
      float a0 = 0.f, a1 = 0.f;
      int u0 = hf * 512;
      for (int u = u0; u < u0 + 512; u += 2) {
        a0 += ah_s[u]     * w[(long)u * 128];
        a1 += ah_s[u + 1] * w[(long)(u + 1) * 128];
      }
      red_s[tid] = a0 + a1;
    }
    __syncthreads();
    if (tid < 128) tanh_s[tid] = tanhf(red_s[tid] + red_s[tid + 128] + P.bg1[tid]);
    __syncthreads();
    if (tid < 64) {
      float tv0 = tanh_s[tid], tv1 = tanh_s[tid + 64];
      float h0 = tv0 * P.Wg2[2 * tid]     + tv1 * P.Wg2[2 * (tid + 64)];
      float h1 = tv0 * P.Wg2[2 * tid + 1] + tv1 * P.Wg2[2 * (tid + 64) + 1];
#pragma unroll
      for (int o = 32; o; o >>= 1) { h0 += __shfl_down(h0, o); h1 += __shfl_down(h1, o); }
      if (tid == 0) {
        float m  = P.mean[b] + expf(h0) * 8.f;
        float sc = expf(h1) * 8.f;
        P.mean[b] = m;
        long pidx = PARAMS_OFF + ((long)b * Tn + t) * 2;
        store_out(P.out, pidx, h0, bf);
        store_out(P.out, pidx + 1, h1, bf);
        bc_s[0] = m; bc_s[1] = sc;
      }
    }
    __syncthreads();
    float m = bc_s[0], sc = bc_s[1];
    int len = P.mlen[b];
    int ci = (int)floorf(fminf(m, 100000.f));
    int l0 = ci - 80; if (l0 < 0) l0 = 0;
    int l1 = ci + 81; if (l1 > len) l1 = len;
    float inv2 = 0.5f / (sc * sc);
    float invZ = 1.f / (2.50662827463100050242f * sc);
    for (int l = l0 + tid; l < l1; l += 256) {
      float d = (float)l - m;
      float al = expf(-d * d * inv2) * invZ;
      alpha_s[l - l0] = al;
      store_out(P.out, ALIGNS_OFF + ((long)b * Tn + t) * Ln + l, al, bf);
    }
    __syncthreads();
    int nl = l1 - l0;
    ST* ctx_all = (ST*)P.ctx_all;
    int e0 = tid * 2;
    float s0 = 0.f, s1 = 0.f;
    if (bf) {
      const unsigned short* mem = (const unsigned short*)P.mem + ((long)b * Ln + l0) * En + e0;
      for (int l = 0; l < nl; ++l) {
        float al = alpha_s[l];
        s0 += al * ldbf(mem, (long)l * En);
        s1 += al * ldbf(mem, (long)l * En + 1);
      }
    } else {
      const float* mem = (const float*)P.mem + ((long)b * Ln + l0) * En + e0;
      for (int l = 0; l < nl; ++l) {
        float al = alpha_s[l];
        s0 += al * mem[(long)l * En];
        s1 += al * mem[(long)l * En + 1];
      }
    }
    P.ctx[b * En + e0] = s0;
    P.ctx[b * En + e0 + 1] = s1;
    st_store(ctx_all, ((long)t * 64 + b) * En + e0, s0);
    st_store(ctx_all, ((long)t * 64 + b) * En + e0 + 1, s1);
  } else {
    if (t == 0) return;
    int bb = bid - 64;                 // 0..31 -> 2 batch rows each
    ST* dh_all = (ST*)P.dh_all;
    for (int i = tid; i < 2048; i += 256) {
      int b = bb * 2 + (i >> 10), u = i & 1023;
      float gi = P.bdi[u]        + P.bdh[u];
      float gf = P.bdi[u + 1024] + P.bdh[u + 1024];
      float gg = P.bdi[u + 2048] + P.bdh[u + 2048];
      float go = P.bdi[u + 3072] + P.bdh[u + 3072];
      for (int kc = 0; kc < DCH; ++kc) {
        const float* pd = P.Pdec + ((long)kc * 64 + b) * G4A;
        gi += pd[u]; gf += pd[u + 1024]; gg += pd[u + 2048]; go += pd[u + 3072];
      }
      float ii = sigm(gi), ff = sigm(gf), oo = sigm(go);
      float cc = ff * P.dc[b * 1024 + u] + ii * tanhf(gg);
      float hh = oo * tanhf(cc);
      P.dc[b * 1024 + u] = cc;
      P.dh[b * 1024 + u] = hh;
      st_store(dh_all, ((long)(t - 1) * 64 + b) * 1024 + u, hh);
    }
  }
}

// ---------------- final projection: logits = [dh, ctx] @ W_proj + b ----------------
template<typename ST>
__global__ __launch_bounds__(256) void k_proj(Ptrs P) {
  __shared__ __align__(16) float A_s[64][65];
  __shared__ __align__(16) float W_s[64 * 160];
  int t = blockIdx.x, tid = threadIdx.x;
  int bf = *P.flag;
  const ST* dh_all = (const ST*)P.dh_all;
  const ST* ctx_all = (const ST*)P.ctx_all;
  int tc = tid & 15, tr = tid >> 4;
  int c0 = tc * 10, b0 = tr * 4;
  float acc[4][10];
#pragma unroll
  for (int i = 0; i < 4; ++i)
#pragma unroll
    for (int j = 0; j < 10; ++j) acc[i][j] = 0.f;
  for (int k0 = 0; k0 < KPROJ; k0 += 64) {
    __syncthreads();
    for (int i = tid; i < 64 * 64; i += 256) {
      int b = i >> 6, kk = i & 63;
      int k = k0 + kk;
      float v = (k < Dn) ? st_load(dh_all, ((long)t * 64 + b) * Dn + k)
                         : st_load(ctx_all, ((long)t * 64 + b) * En + (k - Dn));
      A_s[b][kk] = v;
    }
    for (int i = tid; i < 64 * 160; i += 256) {
      int kk = i / 160, c = i - kk * 160;
      W_s[kk * 160 + c] = (c < Vn) ? P.Wpr[(long)(k0 + kk) * Vn + c] : 0.f;
    }
    __syncthreads();
    for (int kk = 0; kk < 64; ++kk) {
      float xs[4];
#pragma unroll
      for (int i = 0; i < 4; ++i) xs[i] = A_s[b0 + i][kk];
#pragma unroll
      for (int j = 0; j < 10; ++j) {
        float w = W_s[kk * 160 + c0 + j];
#pragma unroll
        for (int i = 0; i < 4; ++i) acc[i][j] += xs[i] * w;
      }
    }
  }
#pragma unroll
  for (int i = 0; i < 4; ++i)
#pragma unroll
    for (int j = 0; j < 10; ++j) {
      int c = c0 + j;
      if (c < Vn) {
        int b = b0 + i;
        store_out(P.out, LOGITS_OFF + ((long)b * Tn + t) * Vn + c, acc[i][j] + P.bpr[c], bf);
      }
    }
}

// ---------------- host ----------------
template<typename ST>
static void run_pipeline(const Ptrs& P, hipStream_t stream) {
  k_prenet<<<Tn * 2, 256, 0, stream>>>(P, DK1.a, DK1.b, DK2.a, DK2.b);
  k_gemm<<<1024, 256, 0, stream>>>(P, -1);          // prologue: att gates for t=0
  for (int t = 0; t <= Tn; ++t) {
    k_point<ST><<<96, 256, 0, stream>>>(P, t);      // att pw(t) + dec pw(t-1)
    if (t < Tn) k_gemm<<<1024, 256, 0, stream>>>(P, t);  // att gates(t+1) + dec gates(t)
  }
  k_proj<ST><<<Tn, 256, 0, stream>>>(P);
}

extern "C" void kernel_launch(void* const* d_in, const int* in_sizes, int n_in,
                              void* d_out, int out_size, void* d_ws, size_t ws_size,
                              hipStream_t stream) {
  (void)in_sizes; (void)n_in; (void)out_size;
  char* base = (char*)d_ws;
  int* flag = (int*)base;
  size_t off = 256;
  auto allocf = [&](size_t n) -> float* {
    float* p = (float*)(base + off);
    off += ((n * 4 + 255) / 256) * 256;
    return p;
  };
  float* Wp1 = allocf(131072);
  float* Wp2 = allocf(65536);
  float* Wai = allocf(3145728);
  float* Wah = allocf(4194304);
  float* bai = allocf(4096);
  float* bah = allocf(4096);
  float* Wg1 = allocf(131072);
  float* bg1 = allocf(128);
  float* Wg2 = allocf(256);
  float* Wdi = allocf(6291456);
  float* Wdh = allocf(4194304);
  float* bdi = allocf(4096);
  float* bdh = allocf(4096);
  float* Wpr = allocf(227328);
  float* bpr = allocf(148);
  float* pre  = allocf((size_t)Tn * 64 * Pn);
  float* Patt = allocf((size_t)ACH * 64 * G4A);
  float* Pdec = allocf((size_t)DCH * 64 * G4A);
  float* ah = allocf(65536);
  float* ac = allocf(65536);
  float* dh = allocf(65536);
  float* dc = allocf(65536);
  float* ctx = allocf(32768);
  float* mean = allocf(64);
  size_t fixed = off;
  size_t nDH = (size_t)Tn * 64 * Dn, nCX = (size_t)Tn * 64 * En;
  bool f32tier = (fixed + (nDH + nCX) * 4 <= ws_size);
  bool b16tier = (fixed + (nDH + nCX) * 2 <= ws_size);
  if (!f32tier && !b16tier) return;

  Ptrs P;
  P.Wp1=Wp1; P.Wp2=Wp2; P.Wai=Wai; P.Wah=Wah; P.bai=bai; P.bah=bah;
  P.Wg1=Wg1; P.bg1=bg1; P.Wg2=Wg2; P.Wdi=Wdi; P.Wdh=Wdh; P.bdi=bdi; P.bdh=bdh;
  P.Wpr=Wpr; P.bpr=bpr;
  P.pre=pre; P.Patt=Patt; P.Pdec=Pdec; P.ah=ah; P.ac=ac; P.dh=dh; P.dc=dc;
  P.ctx=ctx; P.mean=mean;
  size_t esz = f32tier ? 4 : 2;
  P.dh_all  = base + fixed;
  P.ctx_all = base + fixed + nDH * esz;
  P.mem = d_in[0]; P.din = d_in[1]; P.mlen = (const int*)d_in[2];
  P.flag = flag; P.out = d_out;

  k_detect<<<1, 256, 0, stream>>>(d_in[0], flag);

  struct CV { const void* s; float* d; long n; };
  const CV cv[15] = {
    {d_in[3], Wp1, 131072}, {d_in[4], Wp2, 65536}, {d_in[5], Wai, 3145728},
    {d_in[6], Wah, 4194304}, {d_in[7], bai, 4096}, {d_in[8], bah, 4096},
    {d_in[9], Wg1, 131072}, {d_in[10], bg1, 128}, {d_in[11], Wg2, 256},
    {d_in[12], Wdi, 6291456}, {d_in[13], Wdh, 4194304}, {d_in[14], bdi, 4096},
    {d_in[15], bdh, 4096}, {d_in[16], Wpr, 227328}, {d_in[17], bpr, 148},
  };
  for (int i = 0; i < 15; ++i) {
    long g = (cv[i].n + 255) / 256; if (g > 1024) g = 1024;
    k_convert<<<(int)g, 256, 0, stream>>>(cv[i].s, cv[i].d, cv[i].n, flag);
  }
  k_zero_f32<<<512, 256, 0, stream>>>(ah, 65536L * 4 + 32768 + 64);
  k_zero_aligns<<<2048, 256, 0, stream>>>(d_out, flag);

  if (f32tier) run_pipeline<float>(P, stream);
  else         run_pipeline<unsigned short>(P, stream);
}

// Round 3
// 21089.389 us; speedup vs baseline: 3.3303x; 1.8560x over previous
//
#include <hip/hip_runtime.h>
#include <math.h>

// ---------------- config ----------------
#define TF_PARTITIONABLE 1   // jax threefry_partitionable (default True since jax 0.4.36)

static constexpr int Bn=64, Ln=512, En=512, Tn=512, Sn=512, Pn=256, An=1024, Dn=1024, Gn=128, Vn=148;
static constexpr int G4A = 4096;            // 4*A == 4*D
static constexpr int KPROJ = Dn + En;       // 1536
static constexpr int KATT = 1792, KDEC = 2560;
static constexpr int ACH = 4, ACK = 448;    // att gates K = 4 chunks x 448
static constexpr int DCH = 4, DCK = 640;    // dec gates K = 4 chunks x 640
static constexpr int NKB_ATT = KATT / 32;   // 56 k-blocks
static constexpr int NKB_DEC = KDEC / 32;   // 80
static constexpr long LOGITS_OFF = 0;
static constexpr long ALIGNS_OFF = (long)Bn*Tn*Vn;               // 4,849,664
static constexpr long PARAMS_OFF = ALIGNS_OFF + (long)Bn*Tn*Ln;  // 21,626,880

using s16x8 = __attribute__((ext_vector_type(8))) short;
using f32x4 = __attribute__((ext_vector_type(4))) float;

// ---------------- threefry2x32 (jax-exact) ----------------
struct TFo { unsigned a, b; };
static constexpr TFo htf(unsigned k1, unsigned k2, unsigned x0, unsigned x1) {
  unsigned ks2 = k1 ^ k2 ^ 0x1BD11BDAu;
  unsigned ks[3] = {k1, k2, ks2};
  const unsigned ra[4] = {13u,15u,26u,6u}, rb[4] = {17u,29u,16u,24u};
  x0 += k1; x1 += k2;
  for (int g = 0; g < 5; ++g) {
    const unsigned* r = (g % 2 == 0) ? ra : rb;
    for (int i = 0; i < 4; ++i) { x0 += x1; x1 = (x1 << r[i]) | (x1 >> (32u - r[i])); x1 ^= x0; }
    x0 += ks[(g+1)%3]; x1 += ks[(g+2)%3] + (unsigned)(g+1);
  }
  return TFo{x0, x1};
}
#if TF_PARTITIONABLE
static constexpr TFo DK1 = htf(0u,42u,0u,0u);
static constexpr TFo DK2 = htf(0u,42u,0u,1u);
#else
static constexpr TFo S02 = htf(0u,42u,0u,2u);
static constexpr TFo S13 = htf(0u,42u,1u,3u);
static constexpr TFo DK1 = TFo{S02.a, S13.a};
static constexpr TFo DK2 = TFo{S02.b, S13.b};
#endif

__device__ __forceinline__ void dtf(unsigned k1, unsigned k2, unsigned x0, unsigned x1,
                                    unsigned& o0, unsigned& o1) {
  unsigned ks2 = k1 ^ k2 ^ 0x1BD11BDAu;
#define TFR(r) { x0 += x1; x1 = (x1<<r)|(x1>>(32-r)); x1 ^= x0; }
  x0 += k1; x1 += k2;
  TFR(13) TFR(15) TFR(26) TFR(6)  x0 += k2;  x1 += ks2 + 1u;
  TFR(17) TFR(29) TFR(16) TFR(24) x0 += ks2; x1 += k1 + 2u;
  TFR(13) TFR(15) TFR(26) TFR(6)  x0 += k1;  x1 += k2 + 3u;
  TFR(17) TFR(29) TFR(16) TFR(24) x0 += k2;  x1 += ks2 + 4u;
  TFR(13) TFR(15) TFR(26) TFR(6)  x0 += ks2; x1 += k1 + 5u;
#undef TFR
  o0 = x0; o1 = x1;
}

__device__ __forceinline__ bool keepmask(unsigned ka, unsigned kb, unsigned j) {
#if TF_PARTITIONABLE
  unsigned o0, o1; dtf(ka, kb, 0u, j, o0, o1);
  return ((o0 ^ o1) >> 31) == 0u;
#else
  const unsigned H = 4202496u;  // (513*64*256)/2
  unsigned o0, o1;
  if (j < H) { dtf(ka, kb, j, j + H, o0, o1); return (o0 >> 31) == 0u; }
  else       { dtf(ka, kb, j - H, j, o0, o1); return (o1 >> 31) == 0u; }
#endif
}

// ---------------- dtype helpers ----------------
__device__ __forceinline__ float ldbf(const unsigned short* p, long i) {
  return __uint_as_float(((unsigned)p[i]) << 16);
}
__device__ __forceinline__ unsigned short f2bf(float v) {
  unsigned x = __float_as_uint(v);
  return (unsigned short)((x + 0x7fffu + ((x >> 16) & 1u)) >> 16);  // RNE
}
__device__ __forceinline__ void store_out(void* out, long i, float v, int bf) {
  if (bf) ((unsigned short*)out)[i] = f2bf(v);
  else    ((float*)out)[i] = v;
}
__device__ __forceinline__ float st_load(const float* p, long i) { return p[i]; }
__device__ __forceinline__ float st_load(const unsigned short* p, long i) { return ldbf(p, i); }
__device__ __forceinline__ void st_store(float* p, long i, float v) { p[i] = v; }
__device__ __forceinline__ void st_store(unsigned short* p, long i, float v) { p[i] = f2bf(v); }
__device__ __forceinline__ float sigm(float x) { return 1.f / (1.f + expf(-x)); }

// ---------------- pointer pack ----------------
struct Ptrs {
  const float *Wp1,*Wp2,*bai,*bah,*Wg1,*bg1,*Wg2,*bdi,*bdh,*Wpr,*bpr;
  unsigned short *PWatt,*PWdec,*pre_bf,*ah_bf,*ctx_bf,*dh_bf;
  float *Patt,*Pdec,*ah,*ac,*dh,*dc,*ctx,*mean;
  void *dh_all,*ctx_all;
  const void *mem,*din,*w_ai,*w_ah,*w_di,*w_dh;
  const int *mlen; const int *flag; void *out;
};

// ---------------- utility kernels ----------------
__global__ __launch_bounds__(256) void k_detect(const void* mem, int* flag) {
  __shared__ int cnt;
  int tid = threadIdx.x;
  if (tid == 0) cnt = 0;
  __syncthreads();
  const unsigned short* p = (const unsigned short*)mem;
  int local = 0;
  for (int i = tid; i < 1024; i += 256) {
    float f = ldbf(p, 2L * i);
    if (f == f && fabsf(f) > 0.0009f && fabsf(f) < 16.f) local++;
  }
  atomicAdd(&cnt, local);
  __syncthreads();
  if (tid == 0) flag[0] = (cnt > 512) ? 1 : 0;
}

__global__ __launch_bounds__(256) void k_convert(const void* src, float* dst, long n, const int* flag) {
  int bf = *flag;
  long i0 = (long)blockIdx.x * 256 + threadIdx.x, stp = (long)gridDim.x * 256;
  if (bf) { const unsigned short* s = (const unsigned short*)src;
            for (long i = i0; i < n; i += stp) dst[i] = ldbf(s, i); }
  else    { const float* s = (const float*)src;
            for (long i = i0; i < n; i += stp) dst[i] = s[i]; }
}

__global__ __launch_bounds__(256) void k_zero_f32(float* p, long n) {
  for (long i = (long)blockIdx.x * 256 + threadIdx.x; i < n; i += (long)gridDim.x * 256) p[i] = 0.f;
}

__global__ __launch_bounds__(256) void k_zero_aligns(void* out, const int* flag) {
  int bf = *flag;
  unsigned* p; long n;
  if (bf) { p = (unsigned*)out + (ALIGNS_OFF >> 1); n = ((long)Bn*Tn*Ln) >> 1; }
  else    { p = (unsigned*)out + ALIGNS_OFF;        n = (long)Bn*Tn*Ln; }
  for (long i = (long)blockIdx.x * 256 + threadIdx.x; i < n; i += (long)gridDim.x * 256) p[i] = 0u;
}

// ---------------- weight packing: bf16 B-fragment order ----------------
// PW[kblk][nblk][lane][8]: lane l elem j <-> W[kblk*32 + (l>>4)*8 + j][nblk*16 + (l&15)]
// att: W rows 0..767 = W_att_ih, 768..1791 = W_att_hh
// dec: W rows 0..1535 = W_dec_ih, 1536..2559 = W_dec_hh
__global__ __launch_bounds__(256) void k_pack(Ptrs P) {
  __shared__ float s[32][65];
  int bid = blockIdx.x, tid = threadIdx.x;
  bool att = bid < NKB_ATT * 64;
  int lb = att ? bid : bid - NKB_ATT * 64;
  int kblk = lb >> 6, ng = lb & 63;
  int n0 = ng * 64;
  int bf = *P.flag;
  int split = att ? (Pn + En) : (An + En);
  const void* S0 = att ? P.w_ai : P.w_di;
  const void* S1 = att ? P.w_ah : P.w_dh;
  for (int i = tid; i < 2048; i += 256) {
    int kk = i >> 6, n = i & 63;
    int k = kblk * 32 + kk;
    const void* src = (k < split) ? S0 : S1;
    long idx = (long)(k < split ? k : k - split) * G4A + (n0 + n);
    s[kk][n] = bf ? ldbf((const unsigned short*)src, idx) : ((const float*)src)[idx];
  }
  __syncthreads();
  int lane = tid & 63, tb = tid >> 6;
  unsigned short r[8];
#pragma unroll
  for (int j = 0; j < 8; ++j)
    r[j] = f2bf(s[(lane >> 4) * 8 + j][tb * 16 + (lane & 15)]);
  unsigned short* out = (att ? P.PWatt : P.PWdec) +
      (((long)kblk * 256 + (ng * 4 + tb)) * 64 + lane) * 8;
  *(uint4*)out = *(const uint4*)r;
}

// ---------------- prenet (fused GEMM1+mask1+GEMM2+mask2) -> bf16 ----------------
__global__ __launch_bounds__(256) void k_prenet(Ptrs P, unsigned k1a, unsigned k1b,
                                                unsigned k2a, unsigned k2b) {
  __shared__ __align__(16) float x_s[32 * 17];
  __shared__ __align__(16) float W_s[16 * 256];
  __shared__ __align__(16) float h1_s[32 * 258];
  int bid = blockIdx.x, tid = threadIdx.x;
  int t = bid >> 1, half = bid & 1;
  int bf = *P.flag;
  int tc = tid & 63, tr = tid >> 6;
  int p0 = tc * 4, bl0 = tr * 8;
  float acc[8][4];
#pragma unroll
  for (int i = 0; i < 8; ++i) { acc[i][0]=0; acc[i][1]=0; acc[i][2]=0; acc[i][3]=0; }

  for (int kc = 0; kc < 32; ++kc) {
    __syncthreads();
    for (int i = tid; i < 32 * 16; i += 256) {
      int bl = i >> 4, kk = i & 15;
      int s = kc * 16 + kk;
      float v = 0.f;
      if (t > 0) {
        long idx = ((long)(half * 32 + bl) * Sn + s) * Tn + (t - 1);
        v = bf ? ldbf((const unsigned short*)P.din, idx) : ((const float*)P.din)[idx];
      }
      x_s[bl * 17 + kk] = v;
    }
    for (int i = tid; i < 16 * 256; i += 256) {
      int kk = i >> 8, p = i & 255;
      W_s[kk * 256 + p] = P.Wp1[(long)(kc * 16 + kk) * 256 + p];
    }
    __syncthreads();
    for (int kk = 0; kk < 16; ++kk) {
      float4 w = *(const float4*)(W_s + kk * 256 + p0);
#pragma unroll
      for (int i = 0; i < 8; ++i) {
        float x = x_s[(bl0 + i) * 17 + kk];
        acc[i][0] += x * w.x; acc[i][1] += x * w.y; acc[i][2] += x * w.z; acc[i][3] += x * w.w;
      }
    }
  }
#pragma unroll
  for (int i = 0; i < 8; ++i)
#pragma unroll
    for (int j = 0; j < 4; ++j) {
      int bl = bl0 + i, p = p0 + j, bg = half * 32 + bl;
      float v = fmaxf(acc[i][j], 0.f);
      unsigned ft = (unsigned)(((long)t * 64 + bg) * 256 + p);
      v = keepmask(k1a, k1b, ft) ? 2.f * v : 0.f;
      h1_s[bl * 258 + p] = v;
      acc[i][j] = 0.f;
    }
  __syncthreads();
  for (int kc = 0; kc < 16; ++kc) {
    __syncthreads();
    for (int i = tid; i < 16 * 256; i += 256) {
      int kk = i >> 8, p = i & 255;
      W_s[kk * 256 + p] = P.Wp2[(long)(kc * 16 + kk) * 256 + p];
    }
    __syncthreads();
    for (int kk = 0; kk < 16; ++kk) {
      float4 w = *(const float4*)(W_s + kk * 256 + p0);
      int s = kc * 16 + kk;
#pragma unroll
      for (int i = 0; i < 8; ++i) {
        float x = h1_s[(bl0 + i) * 258 + s];
        acc[i][0] += x * w.x; acc[i][1] += x * w.y; acc[i][2] += x * w.z; acc[i][3] += x * w.w;
      }
    }
  }
#pragma unroll
  for (int i = 0; i < 8; ++i)
#pragma unroll
    for (int j = 0; j < 4; ++j) {
      int bg = half * 32 + bl0 + i, p = p0 + j;
      float v = fmaxf(acc[i][j], 0.f);
      unsigned ft = (unsigned)(((long)t * 64 + bg) * 256 + p);
      v = keepmask(k2a, k2b, ft) ? 2.f * v : 0.f;
      P.pre_bf[((long)t * 64 + bg) * 256 + p] = f2bf(v);
    }
}

// ---------------- K1: MFMA gate GEMMs ----------------
// 512 blocks of 256 threads. bid<256: att gates(t+1); else dec gates(t).
// Per GEMM: nb4 = lb>>2 (64 col-groups of 64), kc = lb&3 (K-chunk).
// Wave w covers cols [nb4*64 + w*16, +16), rows 0..63 (4 MFMA tiles), K = chunk.
__global__ __launch_bounds__(256) void k_gemm(Ptrs P, int t) {
  int bid = blockIdx.x, tid = threadIdx.x;
  bool att = bid < 256;
  if (att) { if (t + 1 >= Tn) return; }
  else     { if (t < 0) return; }
  int lb = att ? bid : bid - 256;
  int nb4 = lb >> 2, kc = lb & 3;
  int lane = tid & 63, w = tid >> 6;
  int nblk = nb4 * 4 + w;                       // 16-col block index
  const int NK = att ? (ACK / 32) : (DCK / 32); // 14 or 20
  const int k0 = kc * (att ? ACK : DCK);
  const unsigned short* PW = att ? P.PWatt : P.PWdec;
  const unsigned short* pre_t = P.pre_bf + (long)(t + 1) * 64 * Pn;

  f32x4 acc[4];
#pragma unroll
  for (int i = 0; i < 4; ++i) acc[i] = f32x4{0.f, 0.f, 0.f, 0.f};

  int rlo = lane & 15, khi = (lane >> 4) * 8;

  auto aseg = [&](int kglob, const unsigned short*& seg, int& stride, int& off) {
    if (att) {
      if (kglob < Pn)            { seg = pre_t;    stride = Pn; off = kglob; }
      else if (kglob < Pn + En)  { seg = P.ctx_bf; stride = En; off = kglob - Pn; }
      else                       { seg = P.ah_bf;  stride = An; off = kglob - Pn - En; }
    } else {
      if (kglob < An)            { seg = P.ah_bf;  stride = An; off = kglob; }
      else if (kglob < An + En)  { seg = P.ctx_bf; stride = En; off = kglob - An; }
      else                       { seg = P.dh_bf;  stride = Dn; off = kglob - An - En; }
    }
  };

  uint4 aN[4], bN;
  {
    const unsigned short* seg; int stride, off;
    aseg(k0, seg, stride, off);
    int kloc = off + khi;
#pragma unroll
    for (int mb = 0; mb < 4; ++mb)
      aN[mb] = *(const uint4*)(seg + (long)(mb * 16 + rlo) * stride + kloc);
    bN = *(const uint4*)(PW + (((long)(k0 >> 5) * 256 + nblk) * 64 + lane) * 8);
  }
  for (int kk = 0; kk < NK; ++kk) {
    uint4 aC[4] = {aN[0], aN[1], aN[2], aN[3]};
    uint4 bC = bN;
    if (kk + 1 < NK) {
      int kglob = k0 + (kk + 1) * 32;
      const unsigned short* seg; int stride, off;
      aseg(kglob, seg, stride, off);
      int kloc = off + khi;
#pragma unroll
      for (int mb = 0; mb < 4; ++mb)
        aN[mb] = *(const uint4*)(seg + (long)(mb * 16 + rlo) * stride + kloc);
      bN = *(const uint4*)(PW + (((long)(kglob >> 5) * 256 + nblk) * 64 + lane) * 8);
    }
    s16x8 b = __builtin_bit_cast(s16x8, bC);
#pragma unroll
    for (int mb = 0; mb < 4; ++mb)
      acc[mb] = __builtin_amdgcn_mfma_f32_16x16x32_bf16(
          __builtin_bit_cast(s16x8, aC[mb]), b, acc[mb], 0, 0, 0);
  }
  float* Pout = (att ? P.Patt : P.Pdec) + (long)kc * 64 * G4A;
  int col = nblk * 16 + rlo;
  int rbase = (lane >> 4) * 4;
#pragma unroll
  for (int mb = 0; mb < 4; ++mb)
#pragma unroll
    for (int r = 0; r < 4; ++r)
      Pout[(long)(mb * 16 + rbase + r) * G4A + col] = acc[mb][r];
}

// ---------------- K2: pointwise phase ----------------
// blocks 0..63:  att LSTM pointwise(t) + GMM + alpha + ctx (skip if t >= Tn)
// blocks 64..95: dec LSTM pointwise(t-1) (skip if t == 0)
template<typename ST>
__global__ __launch_bounds__(256) void k_point(Ptrs P, int t) {
  __shared__ float ah_s[1024];
  __shared__ float red_s[256];
  __shared__ float tanh_s[128];
  __shared__ float bc_s[2];
  __shared__ float alpha_s[176];
  int bid = blockIdx.x, tid = threadIdx.x;
  if (bid < 64) {
    if (t >= Tn) return;
    int b = bid;
    int bf = *P.flag;
    for (int u = tid; u < 1024; u += 256) {
      float gi = P.bai[u]        + P.bah[u];
      float gf = P.bai[u + 1024] + P.bah[u + 1024];
      float gg = P.bai[u + 2048] + P.bah[u + 2048];
      float go = P.bai[u + 3072] + P.bah[u + 3072];
      for (int kc = 0; kc < ACH; ++kc) {
        const float* pa = P.Patt + ((long)kc * 64 + b) * G4A;
        gi += pa[u]; gf += pa[u + 1024]; gg += pa[u + 2048]; go += pa[u + 3072];
      }
      float ii = sigm(gi), ff = sigm(gf), oo = sigm(go);
      float cc = ff * P.ac[b * 1024 + u] + ii * tanhf(gg);
      float hh = oo * tanhf(cc);
      P.ac[b * 1024 + u] = cc;
      P.ah[b * 1024 + u] = hh;
      P.ah_bf[b * 1024 + u] = f2bf(hh);
      ah_s[u] = hh;
    }
    __syncthreads();
    {
      int g = tid & 127, hf = tid >> 7;
      const float* w = P.Wg1 + g;
      float a0 = 0.f, a1 = 0.f;
      int u0 = hf * 512;
      for (int u = u0; u < u0 + 512; u += 2) {
        a0 += ah_s[u]     * w[(long)u * 128];
        a1 += ah_s[u + 1] * w[(long)(u + 1) * 128];
      }
      red_s[tid] = a0 + a1;
    }
    __syncthreads();
    if (tid < 128) tanh_s[tid] = tanhf(red_s[tid] + red_s[tid + 128] + P.bg1[tid]);
    __syncthreads();
    if (tid < 64) {
      float tv0 = tanh_s[tid], tv1 = tanh_s[tid + 64];
      float h0 = tv0 * P.Wg2[2 * tid]     + tv1 * P.Wg2[2 * (tid + 64)];
      float h1 = tv0 * P.Wg2[2 * tid + 1] + tv1 * P.Wg2[2 * (tid + 64) + 1];
#pragma unroll
      for (int o = 32; o; o >>= 1) { h0 += __shfl_down(h0, o); h1 += __shfl_down(h1, o); }
      if (tid == 0) {
        float m  = P.mean[b] + expf(h0) * 8.f;
        float sc = expf(h1) * 8.f;
        P.mean[b] = m;
        long pidx = PARAMS_OFF + ((long)b * Tn + t) * 2;
        store_out(P.out, pidx, h0, bf);
        store_out(P.out, pidx + 1, h1, bf);
        bc_s[0] = m; bc_s[1] = sc;
      }
    }
    __syncthreads();
    float m = bc_s[0], sc = bc_s[1];
    int len = P.mlen[b];
    int ci = (int)floorf(fminf(m, 100000.f));
    int l0 = ci - 80; if (l0 < 0) l0 = 0;
    int l1 = ci + 81; if (l1 > len) l1 = len;
    float inv2 = 0.5f / (sc * sc);
    float invZ = 1.f / (2.50662827463100050242f * sc);
    for (int l = l0 + tid; l < l1; l += 256) {
      float d = (float)l - m;
      float al = expf(-d * d * inv2) * invZ;
      alpha_s[l - l0] = al;
      store_out(P.out, ALIGNS_OFF + ((long)b * Tn + t) * Ln + l, al, bf);
    }
    __syncthreads();
    int nl = l1 - l0;
    ST* ctx_all = (ST*)P.ctx_all;
    int e0 = tid * 2;
    float s0 = 0.f, s1 = 0.f;
    if (bf) {
      const unsigned short* mem = (const unsigned short*)P.mem + ((long)b * Ln + l0) * En + e0;
      for (int l = 0; l < nl; ++l) {
        float al = alpha_s[l];
        s0 += al * ldbf(mem, (long)l * En);
        s1 += al * ldbf(mem, (long)l * En + 1);
      }
    } else {
      const float* mem = (const float*)P.mem + ((long)b * Ln + l0) * En + e0;
      for (int l = 0; l < nl; ++l) {
        float al = alpha_s[l];
        s0 += al * mem[(long)l * En];
        s1 += al * mem[(long)l * En + 1];
      }
    }
    P.ctx[b * En + e0] = s0;
    P.ctx[b * En + e0 + 1] = s1;
    P.ctx_bf[b * En + e0] = f2bf(s0);
    P.ctx_bf[b * En + e0 + 1] = f2bf(s1);
    st_store(ctx_all, ((long)t * 64 + b) * En + e0, s0);
    st_store(ctx_all, ((long)t * 64 + b) * En + e0 + 1, s1);
  } else {
    if (t == 0) return;
    int bb = bid - 64;
    ST* dh_all = (ST*)P.dh_all;
    for (int i = tid; i < 2048; i += 256) {
      int b = bb * 2 + (i >> 10), u = i & 1023;
      float gi = P.bdi[u]        + P.bdh[u];
      float gf = P.bdi[u + 1024] + P.bdh[u + 1024];
      float gg = P.bdi[u + 2048] + P.bdh[u + 2048];
      float go = P.bdi[u + 3072] + P.bdh[u + 3072];
      for (int kc = 0; kc < DCH; ++kc) {
        const float* pd = P.Pdec + ((long)kc * 64 + b) * G4A;
        gi += pd[u]; gf += pd[u + 1024]; gg += pd[u + 2048]; go += pd[u + 3072];
      }
      float ii = sigm(gi), ff = sigm(gf), oo = sigm(go);
      float cc = ff * P.dc[b * 1024 + u] + ii * tanhf(gg);
      float hh = oo * tanhf(cc);
      P.dc[b * 1024 + u] = cc;
      P.dh[b * 1024 + u] = hh;
      P.dh_bf[b * 1024 + u] = f2bf(hh);
      st_store(dh_all, ((long)(t - 1) * 64 + b) * 1024 + u, hh);
    }
  }
}

// ---------------- final projection: logits = [dh, ctx] @ W_proj + b ----------------
template<typename ST>
__global__ __launch_bounds__(256) void k_proj(Ptrs P) {
  __shared__ __align__(16) float A_s[64][65];
  __shared__ __align__(16) float W_s[64 * 160];
  int t = blockIdx.x, tid = threadIdx.x;
  int bf = *P.flag;
  const ST* dh_all = (const ST*)P.dh_all;
  const ST* ctx_all = (const ST*)P.ctx_all;
  int tc = tid & 15, tr = tid >> 4;
  int c0 = tc * 10, b0 = tr * 4;
  float acc[4][10];
#pragma unroll
  for (int i = 0; i < 4; ++i)
#pragma unroll
    for (int j = 0; j < 10; ++j) acc[i][j] = 0.f;
  for (int k0 = 0; k0 < KPROJ; k0 += 64) {
    __syncthreads();
    for (int i = tid; i < 64 * 64; i += 256) {
      int b = i >> 6, kk = i & 63;
      int k = k0 + kk;
      float v = (k < Dn) ? st_load(dh_all, ((long)t * 64 + b) * Dn + k)
                         : st_load(ctx_all, ((long)t * 64 + b) * En + (k - Dn));
      A_s[b][kk] = v;
    }
    for (int i = tid; i < 64 * 160; i += 256) {
      int kk = i / 160, c = i - kk * 160;
      W_s[kk * 160 + c] = (c < Vn) ? P.Wpr[(long)(k0 + kk) * Vn + c] : 0.f;
    }
    __syncthreads();
    for (int kk = 0; kk < 64; ++kk) {
      float xs[4];
#pragma unroll
      for (int i = 0; i < 4; ++i) xs[i] = A_s[b0 + i][kk];
#pragma unroll
      for (int j = 0; j < 10; ++j) {
        float w = W_s[kk * 160 + c0 + j];
#pragma unroll
        for (int i = 0; i < 4; ++i) acc[i][j] += xs[i] * w;
      }
    }
  }
#pragma unroll
  for (int i = 0; i < 4; ++i)
#pragma unroll
    for (int j = 0; j < 10; ++j) {
      int c = c0 + j;
      if (c < Vn) {
        int b = b0 + i;
        store_out(P.out, LOGITS_OFF + ((long)b * Tn + t) * Vn + c, acc[i][j] + P.bpr[c], bf);
      }
    }
}

// ---------------- host ----------------
template<typename ST>
static void run_pipeline(const Ptrs& P, hipStream_t stream) {
  k_prenet<<<Tn * 2, 256, 0, stream>>>(P, DK1.a, DK1.b, DK2.a, DK2.b);
  k_gemm<<<512, 256, 0, stream>>>(P, -1);              // prologue: att gates for t=0
  for (int t = 0; t <= Tn; ++t) {
    k_point<ST><<<96, 256, 0, stream>>>(P, t);         // att pw(t) + dec pw(t-1)
    if (t < Tn) k_gemm<<<512, 256, 0, stream>>>(P, t); // att gates(t+1) + dec gates(t)
  }
  k_proj<ST><<<Tn, 256, 0, stream>>>(P);
}

extern "C" void kernel_launch(void* const* d_in, const int* in_sizes, int n_in,
                              void* d_out, int out_size, void* d_ws, size_t ws_size,
                              hipStream_t stream) {
  (void)in_sizes; (void)n_in; (void)out_size;
  char* base = (char*)d_ws;
  int* flag = (int*)base;
  size_t off = 256;
  auto allocf = [&](size_t n) -> float* {
    float* p = (float*)(base + off);
    off += ((n * 4 + 255) / 256) * 256;
    return p;
  };
  auto allocu = [&](size_t n) -> unsigned short* {
    unsigned short* p = (unsigned short*)(base + off);
    off += ((n * 2 + 255) / 256) * 256;
    return p;
  };
  float* Wp1 = allocf(131072);
  float* Wp2 = allocf(65536);
  float* bai = allocf(4096);
  float* bah = allocf(4096);
  float* Wg1 = allocf(131072);
  float* bg1 = allocf(128);
  float* Wg2 = allocf(256);
  float* bdi = allocf(4096);
  float* bdh = allocf(4096);
  float* Wpr = allocf(227328);
  float* bpr = allocf(148);
  unsigned short* PWatt = allocu((size_t)NKB_ATT * 256 * 512);  // 7.34M bf16
  unsigned short* PWdec = allocu((size_t)NKB_DEC * 256 * 512);  // 10.5M bf16
  unsigned short* pre_bf = allocu((size_t)Tn * 64 * Pn);        // 8.4M bf16
  float* Patt = allocf((size_t)ACH * 64 * G4A);                 // 1M f32
  float* Pdec = allocf((size_t)DCH * 64 * G4A);                 // 1M f32
  // fp32 states (contiguous, zeroed together), then bf16 mirrors (contiguous)
  float* ah = allocf(65536);
  float* ac = allocf(65536);
  float* dh = allocf(65536);
  float* dc = allocf(65536);
  float* ctx = allocf(32768);
  float* mean = allocf(64);
  unsigned short* ah_bf = allocu(65536);
  unsigned short* ctx_bf = allocu(32768);
  unsigned short* dh_bf = allocu(65536);
  size_t fixed = off;
  size_t nDH = (size_t)Tn * 64 * Dn, nCX = (size_t)Tn * 64 * En;
  bool f32tier = (fixed + (nDH + nCX) * 4 <= ws_size);
  bool b16tier = (fixed + (nDH + nCX) * 2 <= ws_size);
  if (!f32tier && !b16tier) return;

  Ptrs P;
  P.Wp1=Wp1; P.Wp2=Wp2; P.bai=bai; P.bah=bah; P.Wg1=Wg1; P.bg1=bg1; P.Wg2=Wg2;
  P.bdi=bdi; P.bdh=bdh; P.Wpr=Wpr; P.bpr=bpr;
  P.PWatt=PWatt; P.PWdec=PWdec; P.pre_bf=pre_bf;
  P.ah_bf=ah_bf; P.ctx_bf=ctx_bf; P.dh_bf=dh_bf;
  P.Patt=Patt; P.Pdec=Pdec; P.ah=ah; P.ac=ac; P.dh=dh; P.dc=dc;
  P.ctx=ctx; P.mean=mean;
  size_t esz = f32tier ? 4 : 2;
  P.dh_all  = base + fixed;
  P.ctx_all = base + fixed + nDH * esz;
  P.mem = d_in[0]; P.din = d_in[1]; P.mlen = (const int*)d_in[2];
  P.w_ai = d_in[5]; P.w_ah = d_in[6]; P.w_di = d_in[12]; P.w_dh = d_in[13];
  P.flag = flag; P.out = d_out;

  k_detect<<<1, 256, 0, stream>>>(d_in[0], flag);

  struct CV { const void* s; float* d; long n; };
  const CV cv[11] = {
    {d_in[3], Wp1, 131072}, {d_in[4], Wp2, 65536},
    {d_in[7], bai, 4096}, {d_in[8], bah, 4096},
    {d_in[9], Wg1, 131072}, {d_in[10], bg1, 128}, {d_in[11], Wg2, 256},
    {d_in[14], bdi, 4096}, {d_in[15], bdh, 4096},
    {d_in[16], Wpr, 227328}, {d_in[17], bpr, 148},
  };
  for (int i = 0; i < 11; ++i) {
    long g = (cv[i].n + 255) / 256; if (g > 1024) g = 1024;
    k_convert<<<(int)g, 256, 0, stream>>>(cv[i].s, cv[i].d, cv[i].n, flag);
  }
  k_pack<<<(NKB_ATT + NKB_DEC) * 64, 256, 0, stream>>>(P);
  // zero fp32 states + bf16 mirrors: contiguous from ah:
  // 4*65536 + 32768 + 64 floats, then 163840 u16 (=81920 f32-words); pads are 0-multiple
  k_zero_f32<<<512, 256, 0, stream>>>(ah, 294976 + 81920);
  k_zero_aligns<<<2048, 256, 0, stream>>>(d_out, flag);

  if (f32tier) run_pipeline<float>(P, stream);
  else         run_pipeline<unsigned short>(P, stream);
}